// Round 1
// baseline (9514.952 us; speedup 1.0000x reference)
//
#include <hip/hip_runtime.h>
#include <hip/hip_bf16.h>
#include <hip/hip_cooperative_groups.h>

#define B_ 128
#define T_ 256
#define V_ 256
#define U_ 2048

typedef __bf16 bf16x8 __attribute__((ext_vector_type(8)));
typedef float f32x4 __attribute__((ext_vector_type(4)));

union B8u { uint4 u; bf16x8 v; };

static __device__ inline bf16x8 ldg8(const unsigned short* p) {
    B8u t; t.u = *reinterpret_cast<const uint4*>(p); return t.v;
}
static __device__ inline bf16x8 lds8(const char* smem, unsigned off) {
    B8u t; t.u = *reinterpret_cast<const uint4*>(smem + off); return t.v;
}
static __device__ inline unsigned short f2b(float f) {
    __hip_bfloat16 h = __float2bfloat16(f);
    unsigned short r; __builtin_memcpy(&r, &h, 2); return r;
}

// ---------------- prep kernels ----------------

// out[c][r] = bf16(in[r][c]);  in: [R][C] f32, out: [C][R] bf16
__global__ void transpose_bf16(const float* __restrict__ in,
                               unsigned short* __restrict__ outp, int R, int C) {
    __shared__ float tile[32][33];
    int tc = blockIdx.x * 32, tr = blockIdx.y * 32;
    int lx = threadIdx.x & 31, ly = threadIdx.x >> 5;  // 256 thr: ly 0..7
#pragma unroll
    for (int i = 0; i < 32; i += 8)
        tile[ly + i][lx] = in[(size_t)(tr + ly + i) * C + tc + lx];
    __syncthreads();
#pragma unroll
    for (int i = 0; i < 32; i += 8)
        outp[(size_t)(tc + ly + i) * R + tr + lx] = f2b(tile[lx][ly + i]);
}

__global__ void conv_h0(const float* __restrict__ h0, unsigned short* __restrict__ hb) {
    int i = blockIdx.x * blockDim.x + threadIdx.x;  // grid covers exactly B_*U_
    hb[i] = f2b(h0[i]);
}

// ---------------- main cooperative kernel ----------------
// grid: 256 blocks (4 groups x 64), 256 threads (4 waves), 1 block/CU.
// LDS: WhT slice [32 cols][2048 k] bf16 (128KB, XOR-swizzled) + reduce buf [4][32][33] f32.
__global__ __launch_bounds__(256, 1) void rnn_coop(
        const int* __restrict__ x, const float* __restrict__ Wx,
        const float* __restrict__ bias, const float* __restrict__ bdv,
        const unsigned short* __restrict__ WhT, const unsigned short* __restrict__ WdT,
        unsigned short* __restrict__ hbuf, float* __restrict__ out) {
    extern __shared__ char smem[];
    float* red = (float*)(smem + 32 * 2048 * 2);  // [4][32][33] f32

    const int bid = blockIdx.x;
    const int g = bid >> 6, p = bid & 63;
    const int b0 = g * 32, c0 = p * 32;
    const int tid = threadIdx.x;
    const int w = tid >> 6, lane = tid & 63;
    const int lr = lane & 15, lh = lane >> 4;

    // Fill Wh LDS slice: lds[(c*4096 + k8*16) ^ ((c&7)<<4)] = WhT[c0+c][k8*8..+8]
    for (int i = tid; i < 32 * 256; i += 256) {
        int c = i >> 8, k8 = i & 255;
        uint4 v = *reinterpret_cast<const uint4*>(WhT + (size_t)(c0 + c) * U_ + k8 * 8);
        unsigned off = (unsigned)(c * 4096 + k8 * 16) ^ ((unsigned)(c & 7) << 4);
        *reinterpret_cast<uint4*>(smem + off) = v;
    }
    __syncthreads();

    cooperative_groups::grid_group grid = cooperative_groups::this_grid();

    for (int t = 0; t <= T_; ++t) {
        const unsigned short* hprev = hbuf + ((t & 1) ^ 1) * (B_ * U_);
        unsigned short* hcur = hbuf + (t & 1) * (B_ * U_);

        if (t < T_) {
            // ---- recurrence: out[32 batches, 32 cols], wave w takes K-quarter ----
            const int kbase = w * 512 + lh * 8;
            const unsigned short* pa0 = hprev + (size_t)(b0 + lr) * U_ + kbase;
            const unsigned short* pa1 = pa0 + 16 * U_;
            const unsigned lin0 = (unsigned)(lr * 4096) + (unsigned)(kbase * 2);
            const unsigned lin1 = lin0 + 16 * 4096;
            const unsigned swz = (unsigned)(lr & 7) << 4;
            f32x4 acc00 = {0.f, 0.f, 0.f, 0.f}, acc01 = {0.f, 0.f, 0.f, 0.f};
            f32x4 acc10 = {0.f, 0.f, 0.f, 0.f}, acc11 = {0.f, 0.f, 0.f, 0.f};
#pragma unroll
            for (int ks = 0; ks < 16; ++ks) {
                bf16x8 a0 = ldg8(pa0 + ks * 32);
                bf16x8 a1 = ldg8(pa1 + ks * 32);
                bf16x8 bb0 = lds8(smem, (lin0 + (unsigned)ks * 64) ^ swz);
                bf16x8 bb1 = lds8(smem, (lin1 + (unsigned)ks * 64) ^ swz);
                acc00 = __builtin_amdgcn_mfma_f32_16x16x32_bf16(a0, bb0, acc00, 0, 0, 0);
                acc01 = __builtin_amdgcn_mfma_f32_16x16x32_bf16(a0, bb1, acc01, 0, 0, 0);
                acc10 = __builtin_amdgcn_mfma_f32_16x16x32_bf16(a1, bb0, acc10, 0, 0, 0);
                acc11 = __builtin_amdgcn_mfma_f32_16x16x32_bf16(a1, bb1, acc11, 0, 0, 0);
            }
            // write split-K partials (C-layout: col=lane&15, row=(lane>>4)*4+r)
            float* redw = red + w * (32 * 33);
#pragma unroll
            for (int r = 0; r < 4; ++r) {
                redw[(lh * 4 + r) * 33 + lr] = acc00[r];
                redw[(lh * 4 + r) * 33 + 16 + lr] = acc01[r];
                redw[(16 + lh * 4 + r) * 33 + lr] = acc10[r];
                redw[(16 + lh * 4 + r) * 33 + 16 + lr] = acc11[r];
            }
            __syncthreads();
            // reduce: wave w owns 16x16 tile (mi=w>>1, ni=w&1); f32 epilogue
            const int mi = w >> 1, ni = w & 1;
#pragma unroll
            for (int r = 0; r < 4; ++r) {
                int row = mi * 16 + lh * 4 + r;
                int col = ni * 16 + lr;
                float z = red[0 * (32 * 33) + row * 33 + col] + red[1 * (32 * 33) + row * 33 + col] +
                          red[2 * (32 * 33) + row * 33 + col] + red[3 * (32 * 33) + row * 33 + col];
                int bi = b0 + row;
                int u = c0 + col;
                int tok = x[bi * T_ + t];
                float xp = Wx[(size_t)tok * U_ + u] + bias[u];
                float h = tanhf(z + xp);
                hcur[(size_t)bi * U_ + u] = f2b(h);
            }
        }

        // ---- fused decoder for step s=t-1 (uses h_{t-1}=hprev, already needed) ----
        // block p: v-tile (p&15)*16, K-chunk (p>>4)*512; waves 0,1 take 16-batch halves
        if (t >= 1 && w < 2) {
            const int s = t - 1;
            const int vt = p & 15, kc = p >> 4;
            const int v0 = vt * 16;
            const int kb = kc * 512 + lh * 8;
            const unsigned short* pa = hprev + (size_t)(b0 + 16 * w + lr) * U_ + kb;
            const unsigned short* pb = WdT + (size_t)(v0 + lr) * U_ + kb;
            f32x4 acc = {0.f, 0.f, 0.f, 0.f};
#pragma unroll
            for (int ks = 0; ks < 16; ++ks) {
                bf16x8 a = ldg8(pa + ks * 32);
                bf16x8 bb = ldg8(pb + ks * 32);
                acc = __builtin_amdgcn_mfma_f32_16x16x32_bf16(a, bb, acc, 0, 0, 0);
            }
#pragma unroll
            for (int r = 0; r < 4; ++r) {
                int bi = b0 + 16 * w + lh * 4 + r;
                int v = v0 + lr;
                float val = acc[r];
                if (kc == 0) val += bdv[v];
                atomicAdd(out + ((size_t)bi * T_ + s) * V_ + v, val);
            }
        }

        grid.sync();
    }
}

// ---------------- launch ----------------
extern "C" void kernel_launch(void* const* d_in, const int* in_sizes, int n_in,
                              void* d_out, int out_size, void* d_ws, size_t ws_size,
                              hipStream_t stream) {
    const int* x = (const int*)d_in[0];
    const float* Wx = (const float*)d_in[1];
    const float* Wh = (const float*)d_in[2];
    const float* b = (const float*)d_in[3];
    const float* Wd = (const float*)d_in[4];
    const float* bd = (const float*)d_in[5];
    const float* h0 = (const float*)d_in[6];
    float* out = (float*)d_out;

    char* ws = (char*)d_ws;
    unsigned short* WhT = (unsigned short*)ws;                    // 8,388,608 B
    unsigned short* WdT = (unsigned short*)(ws + 8388608);        // 1,048,576 B
    unsigned short* hbuf = (unsigned short*)(ws + 9437184);       // 1,048,576 B (double buf)

    // decoder accumulates with atomics -> out must start at zero every call
    hipMemsetAsync(d_out, 0, (size_t)out_size * sizeof(float), stream);

    transpose_bf16<<<dim3(64, 64), 256, 0, stream>>>(Wh, WhT, 2048, 2048);
    transpose_bf16<<<dim3(8, 64), 256, 0, stream>>>(Wd, WdT, 2048, 256);
    conv_h0<<<1024, 256, 0, stream>>>(h0, hbuf + B_ * U_);  // h_{-1} into buffer 1

    const int smem_bytes = 32 * 2048 * 2 + 4 * 32 * 33 * 4;  // 147,968 B
    hipFuncSetAttribute((const void*)rnn_coop, hipFuncAttributeMaxDynamicSharedMemorySize,
                        smem_bytes);

    void* args[] = {(void*)&x, (void*)&Wx, (void*)&b,    (void*)&bd,
                    (void*)&WhT, (void*)&WdT, (void*)&hbuf, (void*)&out};
    hipLaunchCooperativeKernel((const void*)rnn_coop, dim3(256), dim3(256), args,
                               (unsigned)smem_bytes, stream);
}

// Round 2
// 2531.242 us; speedup vs baseline: 3.7590x; 3.7590x over previous
//
#include <hip/hip_runtime.h>
#include <hip/hip_bf16.h>

#define B_ 128
#define T_ 256
#define V_ 256
#define U_ 2048
#define GRP_BLKS 64

typedef __bf16 bf16x8 __attribute__((ext_vector_type(8)));
typedef float f32x4 __attribute__((ext_vector_type(4)));

union B8u { uint4 u; bf16x8 v; };

static __device__ inline bf16x8 u2b(uint4 u) { B8u t; t.u = u; return t.v; }
static __device__ inline bf16x8 ldg8(const unsigned short* p) {
    B8u t; t.u = *reinterpret_cast<const uint4*>(p); return t.v;
}
static __device__ inline bf16x8 lds8(const char* smem, unsigned off) {
    B8u t; t.u = *reinterpret_cast<const uint4*>(smem + off); return t.v;
}
static __device__ inline unsigned short f2b(float f) {
    __hip_bfloat16 h = __float2bfloat16(f);
    unsigned short r; __builtin_memcpy(&r, &h, 2); return r;
}

// device-coherent (L1+L2-bypassing, L3 coherence point) load/store for h
static __device__ inline uint4 ldg16_sc(const unsigned short* p) {
    uint4 r;
    asm volatile("global_load_dwordx4 %0, %1, off sc0 sc1"
                 : "=&v"(r) : "v"(p) : "memory");
    return r;
}
static __device__ inline void stg4_sc(unsigned short* p, unsigned v) {
    asm volatile("global_store_dword %0, %1, off sc0 sc1"
                 :: "v"(p), "v"(v) : "memory");
}

// ---------------- prep kernels ----------------

// out[c][r] = bf16(in[r][c]);  in: [R][C] f32, out: [C][R] bf16
__global__ void transpose_bf16(const float* __restrict__ in,
                               unsigned short* __restrict__ outp, int R, int C) {
    __shared__ float tile[32][33];
    int tc = blockIdx.x * 32, tr = blockIdx.y * 32;
    int lx = threadIdx.x & 31, ly = threadIdx.x >> 5;  // 256 thr: ly 0..7
#pragma unroll
    for (int i = 0; i < 32; i += 8)
        tile[ly + i][lx] = in[(size_t)(tr + ly + i) * C + tc + lx];
    __syncthreads();
#pragma unroll
    for (int i = 0; i < 32; i += 8)
        outp[(size_t)(tc + ly + i) * R + tr + lx] = f2b(tile[lx][ly + i]);
}

__global__ void conv_h0(const float* __restrict__ h0, unsigned short* __restrict__ hb) {
    int i = blockIdx.x * blockDim.x + threadIdx.x;  // grid covers exactly B_*U_
    hb[i] = f2b(h0[i]);
}

// ---------------- main cooperative kernel ----------------
// grid: 256 blocks (4 groups x 64), 256 threads (4 waves), 1 block/CU.
// LDS: WhT slice [32 cols][2048 k] bf16 (128KB, XOR-swizzled) + reduce buf [4][32][34] f32.
// Sync: per-group 64-block counter barrier (agent-relaxed atomics, NO L2 inv/wb).
// h: triple-buffered, all accesses sc0sc1 (L3-coherent). Decoder runs between
// arrive and wait, hiding in the barrier window.
__global__ __launch_bounds__(256, 1) void rnn_coop(
        const int* __restrict__ x, const float* __restrict__ Wx,
        const float* __restrict__ bias, const float* __restrict__ bdv,
        const unsigned short* __restrict__ WhT, const unsigned short* __restrict__ WdT,
        unsigned short* __restrict__ hbuf, float* __restrict__ out,
        unsigned* __restrict__ ctrs) {
    extern __shared__ char smem[];
    float* red = (float*)(smem + 32 * 2048 * 2);  // [4][32][34] f32

    const int bid = blockIdx.x;
    const int g = bid >> 6, p = bid & 63;
    const int b0 = g * 32, c0 = p * 32;
    const int tid = threadIdx.x;
    const int w = tid >> 6, lane = tid & 63;
    const int lr = lane & 15, lh = lane >> 4;
    unsigned* gctr = ctrs + g * 64;  // 256B-spaced per-group counters

    // Fill Wh LDS slice: lds[(c*4096 + k8*16) ^ ((c&7)<<4)] = WhT[c0+c][k8*8..+8]
    for (int i = tid; i < 32 * 256; i += 256) {
        int c = i >> 8, k8 = i & 255;
        uint4 v = *reinterpret_cast<const uint4*>(WhT + (size_t)(c0 + c) * U_ + k8 * 8);
        unsigned off = (unsigned)(c * 4096 + k8 * 16) ^ ((unsigned)(c & 7) << 4);
        *reinterpret_cast<uint4*>(smem + off) = v;
    }
    __syncthreads();

    for (int t = 0; t <= T_; ++t) {
        // h_s lives in buf[s%3]; step t reads h_{t-1} from buf[(t+2)%3]
        const unsigned short* hprev = hbuf + (size_t)((t + 2) % 3) * (B_ * U_);
        unsigned short* hcur = hbuf + (size_t)(t % 3) * (B_ * U_);

        if (t < T_) {
            // ---- recurrence: out[32 batches, 32 cols], wave w takes K-quarter ----
            const int kbase = w * 512 + lh * 8;
            const unsigned short* pa0 = hprev + (size_t)(b0 + lr) * U_ + kbase;
            const unsigned short* pa1 = pa0 + 16 * U_;
            const unsigned lin0 = (unsigned)(lr * 4096) + (unsigned)(kbase * 2);
            const unsigned lin1 = lin0 + 16 * 4096;
            const unsigned swz = (unsigned)(lr & 7) << 4;

            // issue all 32 coherent A-loads, then one wait (asm loads are
            // untracked by the compiler -> manual vmcnt + sched fence)
            uint4 areg0[16], areg1[16];
#pragma unroll
            for (int ks = 0; ks < 16; ++ks) {
                areg0[ks] = ldg16_sc(pa0 + ks * 32);
                areg1[ks] = ldg16_sc(pa1 + ks * 32);
            }
            asm volatile("s_waitcnt vmcnt(0)" ::: "memory");
            __builtin_amdgcn_sched_barrier(0);

            f32x4 acc00 = {0.f, 0.f, 0.f, 0.f}, acc01 = {0.f, 0.f, 0.f, 0.f};
            f32x4 acc10 = {0.f, 0.f, 0.f, 0.f}, acc11 = {0.f, 0.f, 0.f, 0.f};
#pragma unroll
            for (int ks = 0; ks < 16; ++ks) {
                bf16x8 a0 = u2b(areg0[ks]);
                bf16x8 a1 = u2b(areg1[ks]);
                bf16x8 bb0 = lds8(smem, (lin0 + (unsigned)ks * 64) ^ swz);
                bf16x8 bb1 = lds8(smem, (lin1 + (unsigned)ks * 64) ^ swz);
                acc00 = __builtin_amdgcn_mfma_f32_16x16x32_bf16(a0, bb0, acc00, 0, 0, 0);
                acc01 = __builtin_amdgcn_mfma_f32_16x16x32_bf16(a0, bb1, acc01, 0, 0, 0);
                acc10 = __builtin_amdgcn_mfma_f32_16x16x32_bf16(a1, bb0, acc10, 0, 0, 0);
                acc11 = __builtin_amdgcn_mfma_f32_16x16x32_bf16(a1, bb1, acc11, 0, 0, 0);
            }
            // write split-K partials (C-layout: col=lane&15, row=(lane>>4)*4+r)
            float* redw = red + w * (32 * 34);
#pragma unroll
            for (int r = 0; r < 4; ++r) {
                redw[(lh * 4 + r) * 34 + lr] = acc00[r];
                redw[(lh * 4 + r) * 34 + 16 + lr] = acc01[r];
                redw[(16 + lh * 4 + r) * 34 + lr] = acc10[r];
                redw[(16 + lh * 4 + r) * 34 + 16 + lr] = acc11[r];
            }
            __syncthreads();
            // reduce: wave w owns 16x16 tile (mi=w>>1, ni=w&1); f32 epilogue;
            // each lane: 2 rows x 1 col-pair -> packed dword coherent store
            const int mi = w >> 1, ni = w & 1;
            const int rb = lane >> 3;      // 0..7
            const int cc = (lane & 7) * 2; // even col in tile
#pragma unroll
            for (int s = 0; s < 2; ++s) {
                int row = mi * 16 + rb + 8 * s;
                int col = ni * 16 + cc;
                float z0 = 0.f, z1 = 0.f;
#pragma unroll
                for (int q = 0; q < 4; ++q) {
                    float2 v = *reinterpret_cast<float2*>(&red[q * (32 * 34) + row * 34 + col]);
                    z0 += v.x; z1 += v.y;
                }
                int bi = b0 + row;
                int u = c0 + col;
                int tok = x[bi * T_ + t];
                float xp0 = Wx[(size_t)tok * U_ + u] + bias[u];
                float xp1 = Wx[(size_t)tok * U_ + u + 1] + bias[u + 1];
                float h0f = tanhf(z0 + xp0);
                float h1f = tanhf(z1 + xp1);
                unsigned pk = (unsigned)f2b(h0f) | ((unsigned)f2b(h1f) << 16);
                stg4_sc(hcur + (size_t)bi * U_ + u, pk);
            }

            // ---- barrier arrive: my h_t is visible once vmcnt drains ----
            asm volatile("s_waitcnt vmcnt(0)" ::: "memory");
            __syncthreads();  // all 4 waves' stores drained
            if (tid == 0)
                __hip_atomic_fetch_add(gctr, 1u, __ATOMIC_RELAXED, __HIP_MEMORY_SCOPE_AGENT);
        }

        // ---- fused decoder for step s=t-1 (reads hprev = buf[(t+2)%3]);
        //      runs between arrive and wait -> hides in barrier window.
        //      Safe: buf[(t+2)%3] is next overwritten at step t+2, which is
        //      gated on arrive(t+1), which I only do after this completes. ----
        if (t >= 1 && w < 2) {
            const int vt = p & 15, kc = p >> 4;
            const int v0 = vt * 16;
            const int kb = kc * 512 + lh * 8;
            const unsigned short* pa = hprev + (size_t)(b0 + 16 * w + lr) * U_ + kb;
            const unsigned short* pb = WdT + (size_t)(v0 + lr) * U_ + kb;
            uint4 preg[16];
#pragma unroll
            for (int ks = 0; ks < 16; ++ks) preg[ks] = ldg16_sc(pa + ks * 32);
            asm volatile("s_waitcnt vmcnt(0)" ::: "memory");
            __builtin_amdgcn_sched_barrier(0);
            f32x4 acc = {0.f, 0.f, 0.f, 0.f};
#pragma unroll
            for (int ks = 0; ks < 16; ++ks) {
                bf16x8 bb = ldg8(pb + ks * 32);
                acc = __builtin_amdgcn_mfma_f32_16x16x32_bf16(u2b(preg[ks]), bb, acc, 0, 0, 0);
            }
            const int s = t - 1;
#pragma unroll
            for (int r = 0; r < 4; ++r) {
                int bi = b0 + 16 * w + lh * 4 + r;
                int v = v0 + lr;
                float val = acc[r];
                if (kc == 0) val += bdv[v];
                atomicAdd(out + ((size_t)bi * T_ + s) * V_ + v, val);
            }
        }

        if (t < T_) {
            // ---- barrier wait: all 64 group blocks arrived for step t ----
            if (tid == 0) {
                unsigned tgt = (unsigned)(t + 1) * GRP_BLKS;
                while (__hip_atomic_load(gctr, __ATOMIC_RELAXED, __HIP_MEMORY_SCOPE_AGENT) < tgt)
                    __builtin_amdgcn_s_sleep(1);
            }
            __syncthreads();
        }
    }
}

// ---------------- launch ----------------
extern "C" void kernel_launch(void* const* d_in, const int* in_sizes, int n_in,
                              void* d_out, int out_size, void* d_ws, size_t ws_size,
                              hipStream_t stream) {
    const int* x = (const int*)d_in[0];
    const float* Wx = (const float*)d_in[1];
    const float* Wh = (const float*)d_in[2];
    const float* b = (const float*)d_in[3];
    const float* Wd = (const float*)d_in[4];
    const float* bd = (const float*)d_in[5];
    const float* h0 = (const float*)d_in[6];
    float* out = (float*)d_out;

    char* ws = (char*)d_ws;
    unsigned short* WhT = (unsigned short*)ws;                     // 8,388,608 B
    unsigned short* WdT = (unsigned short*)(ws + 8388608);         // 1,048,576 B
    unsigned short* hbuf = (unsigned short*)(ws + 9437184);        // 3 x 524,288 B
    unsigned* ctrs = (unsigned*)(ws + 11010048);                   // 4 x 256 B

    // decoder accumulates with atomics -> out must start at zero every call;
    // barrier counters must start at zero every call
    hipMemsetAsync(d_out, 0, (size_t)out_size * sizeof(float), stream);
    hipMemsetAsync(ctrs, 0, 1024, stream);

    transpose_bf16<<<dim3(64, 64), 256, 0, stream>>>(Wh, WhT, 2048, 2048);
    transpose_bf16<<<dim3(8, 64), 256, 0, stream>>>(Wd, WdT, 2048, 256);
    conv_h0<<<1024, 256, 0, stream>>>(h0, hbuf + 2 * (B_ * U_));  // h_{-1} -> buf[2]

    const int smem_bytes = 32 * 2048 * 2 + 4 * 32 * 34 * 4;  // 148,480 B
    hipFuncSetAttribute((const void*)rnn_coop, hipFuncAttributeMaxDynamicSharedMemorySize,
                        smem_bytes);

    void* args[] = {(void*)&x,   (void*)&Wx,  (void*)&b,    (void*)&bd,  (void*)&WhT,
                    (void*)&WdT, (void*)&hbuf, (void*)&out, (void*)&ctrs};
    hipLaunchCooperativeKernel((const void*)rnn_coop, dim3(256), dim3(256), args,
                               (unsigned)smem_bytes, stream);
}